// Round 2
// baseline (46.488 us; speedup 1.0000x reference)
//
#include <hip/hip_runtime.h>

#define IMG_H 1024
#define IMG_W 1024

// Separable Sobel:
//   SOBEL_X = [1,2,1]^T (vert) x [-1,0,1] (horiz)
//   SOBEL_Y = [-1,0,1]^T (vert) x [ 1,2,1] (horiz)
// Zero padding = 1. Per-thread: one 4x4 block, window = 6x6.
__device__ __forceinline__ void var_from_win(const float w[6][6],
                                             float& varX, float& varY) {
    float hA[6][4];  // horizontal [-1,0,1]
    float hB[6][4];  // horizontal [ 1,2,1]
#pragma unroll
    for (int ry = 0; ry < 6; ++ry) {
#pragma unroll
        for (int c = 0; c < 4; ++c) {
            hA[ry][c] = w[ry][c + 2] - w[ry][c];
            hB[ry][c] = w[ry][c] + 2.f * w[ry][c + 1] + w[ry][c + 2];
        }
    }
    float sX = 0.f, sX2 = 0.f, sY = 0.f, sY2 = 0.f;
#pragma unroll
    for (int yy = 0; yy < 4; ++yy) {
#pragma unroll
        for (int c = 0; c < 4; ++c) {
            float gx = hA[yy][c] + 2.f * hA[yy + 1][c] + hA[yy + 2][c];
            float gy = hB[yy + 2][c] - hB[yy][c];
            sX += gx; sX2 += gx * gx;
            sY += gy; sY2 += gy * gy;
        }
    }
    float mX = sX * 0.0625f, mY = sY * 0.0625f;
    varX = sX2 * 0.0625f - mX * mX;
    varY = sY2 * 0.0625f - mY * mY;
}

// Grid: 16 images * 16*16 tiles = 4096 workgroups of 256 threads.
// Each workgroup covers a 64x64 pixel tile (16x16 blocks of 4x4).
// Key structure: ALL 36 global loads (both images' 6x6 windows) are issued
// before any compute, pinned by sched_barrier(0), so HBM latency is hidden
// by memory-level parallelism instead of occupancy.
__global__ __launch_bounds__(256) void gvl_main(const float* __restrict__ A,
                                                const float* __restrict__ B,
                                                float* __restrict__ partial) {
    int wg   = blockIdx.x;
    int img  = wg >> 8;
    int tile = wg & 255;
    int ty = tile >> 4, tx = tile & 15;
    int t  = threadIdx.x;
    int by = t >> 4, bx = t & 15;
    int py = ty * 64 + by * 4;
    int px = tx * 64 + bx * 4;
    size_t base = (size_t)img * (size_t)(IMG_H * IMG_W);

    float wa[6][6], wb[6][6];
#pragma unroll
    for (int ry = 0; ry < 6; ++ry) {
        int y = py - 1 + ry;
        bool inr = (unsigned)y < (unsigned)IMG_H;
        const float* ra = A + base + (size_t)(inr ? y : 0) * IMG_W;
        const float* rb = B + base + (size_t)(inr ? y : 0) * IMG_W;
        float4 ma = make_float4(0.f, 0.f, 0.f, 0.f);
        float4 mb = make_float4(0.f, 0.f, 0.f, 0.f);
        float a0 = 0.f, a5 = 0.f, b0 = 0.f, b5 = 0.f;
        if (inr) {
            ma = *reinterpret_cast<const float4*>(ra + px);
            mb = *reinterpret_cast<const float4*>(rb + px);
            if (px > 0)           { a0 = ra[px - 1]; b0 = rb[px - 1]; }
            if (px + 4 < IMG_W)   { a5 = ra[px + 4]; b5 = rb[px + 4]; }
        }
        wa[ry][0] = a0;   wa[ry][1] = ma.x; wa[ry][2] = ma.y;
        wa[ry][3] = ma.z; wa[ry][4] = ma.w; wa[ry][5] = a5;
        wb[ry][0] = b0;   wb[ry][1] = mb.x; wb[ry][2] = mb.y;
        wb[ry][3] = mb.z; wb[ry][4] = mb.w; wb[ry][5] = b5;
    }
    // Pin: every load above stays above; compute below waits per-register.
    __builtin_amdgcn_sched_barrier(0);

    float vXa, vYa, vXb, vYb;
    var_from_win(wa, vXa, vYa);
    var_from_win(wb, vXb, vYb);

    float dX = vXa - vXb, dY = vYa - vYb;
    float val = dX * dX + dY * dY;

    // wave (64-lane) tree reduction
#pragma unroll
    for (int off = 32; off > 0; off >>= 1) val += __shfl_down(val, off);
    __shared__ float ws[4];
    if ((t & 63) == 0) ws[t >> 6] = val;
    __syncthreads();
    if (t == 0) partial[wg] = ws[0] + ws[1] + ws[2] + ws[3];
}

__global__ __launch_bounds__(256) void gvl_final(const float* __restrict__ partial,
                                                 float* __restrict__ out) {
    int t = threadIdx.x;
    float s = 0.f;
#pragma unroll
    for (int i = 0; i < 16; ++i) s += partial[t + i * 256];
#pragma unroll
    for (int off = 32; off > 0; off >>= 1) s += __shfl_down(s, off);
    __shared__ float ws[4];
    if ((t & 63) == 0) ws[t >> 6] = s;
    __syncthreads();
    if (t == 0) out[0] = ws[0] + ws[1] + ws[2] + ws[3];
}

extern "C" void kernel_launch(void* const* d_in, const int* in_sizes, int n_in,
                              void* d_out, int out_size, void* d_ws, size_t ws_size,
                              hipStream_t stream) {
    const float* out_img = (const float*)d_in[0];
    const float* tgt_img = (const float*)d_in[1];
    float* partial = (float*)d_ws;   // 4096 floats = 16 KB
    gvl_main<<<4096, 256, 0, stream>>>(out_img, tgt_img, partial);
    gvl_final<<<1, 256, 0, stream>>>(partial, (float*)d_out);
}

// Round 3
// 45.838 us; speedup vs baseline: 1.0142x; 1.0142x over previous
//
#include <hip/hip_runtime.h>

#define IMG_H 1024
#define IMG_W 1024

// Separable Sobel, zero padding 1:
//   SOBEL_X = [1,2,1]^T (vert) x [-1,0,1] (horiz)
//   SOBEL_Y = [-1,0,1]^T (vert) x [ 1,2,1] (horiz)
// Per-thread: one 4x4 block; 6x6 window held in registers.
// m[ry] = cols px..px+3, l[ry]/r[ry] = halo cols px-1 / px+4 (clamped loads,
// masked after), my[ry] = row-in-range mask, mlc/mrc = halo-col masks.
__device__ __forceinline__ void sobel_var(const float4 m[6], const float l[6],
                                          const float r[6], const float my[6],
                                          float mlc, float mrc,
                                          float& varX, float& varY) {
    float hA[6][4];  // horizontal [-1,0,1]
    float hB[6][4];  // horizontal [ 1,2,1]
#pragma unroll
    for (int ry = 0; ry < 6; ++ry) {
        float w0 = l[ry] * mlc * my[ry];
        float w1 = m[ry].x * my[ry];
        float w2 = m[ry].y * my[ry];
        float w3 = m[ry].z * my[ry];
        float w4 = m[ry].w * my[ry];
        float w5 = r[ry] * mrc * my[ry];
        hA[ry][0] = w2 - w0;
        hA[ry][1] = w3 - w1;
        hA[ry][2] = w4 - w2;
        hA[ry][3] = w5 - w3;
        hB[ry][0] = w0 + 2.f * w1 + w2;
        hB[ry][1] = w1 + 2.f * w2 + w3;
        hB[ry][2] = w2 + 2.f * w3 + w4;
        hB[ry][3] = w3 + 2.f * w4 + w5;
    }
    float sX = 0.f, sX2 = 0.f, sY = 0.f, sY2 = 0.f;
#pragma unroll
    for (int yy = 0; yy < 4; ++yy) {
#pragma unroll
        for (int c = 0; c < 4; ++c) {
            float gx = hA[yy][c] + 2.f * hA[yy + 1][c] + hA[yy + 2][c];
            float gy = hB[yy + 2][c] - hB[yy][c];
            sX += gx; sX2 += gx * gx;
            sY += gy; sY2 += gy * gy;
        }
    }
    float mX = sX * 0.0625f, mY = sY * 0.0625f;
    varX = sX2 * 0.0625f - mX * mX;
    varY = sY2 * 0.0625f - mY * mY;
}

// Grid: 16 images * 16*16 tiles = 4096 workgroups of 256 threads.
// Each workgroup covers a 64x64 pixel tile (16x16 blocks of 4x4).
// Loads are BRANCH-FREE (clamped addresses + masks) so all 36 per-thread
// loads issue in one batch before any compute -> MLP hides HBM latency.
__global__ __launch_bounds__(256) void gvl_main(const float* __restrict__ A,
                                                const float* __restrict__ B,
                                                float* __restrict__ partial) {
    int wg   = blockIdx.x;
    int img  = wg >> 8;
    int tile = wg & 255;
    int ty = tile >> 4, tx = tile & 15;
    int t  = threadIdx.x;
    int by = t >> 4, bx = t & 15;
    int py = ty * 64 + by * 4;
    int px = tx * 64 + bx * 4;
    const size_t base = (size_t)img * (size_t)(IMG_H * IMG_W);
    const float* Ab = A + base;
    const float* Bb = B + base;

    int   xl  = (px > 0) ? px - 1 : 0;
    int   xr  = (px + 4 < IMG_W) ? px + 4 : IMG_W - 1;
    float mlc = (px > 0) ? 1.f : 0.f;
    float mrc = (px + 4 < IMG_W) ? 1.f : 0.f;

    float4 am[6], bm[6];
    float  al[6], ar[6], bl[6], br[6], my[6];
#pragma unroll
    for (int ry = 0; ry < 6; ++ry) {
        int y = py - 1 + ry;
        my[ry] = ((unsigned)y < (unsigned)IMG_H) ? 1.f : 0.f;
        int yc = y < 0 ? 0 : (y > IMG_H - 1 ? IMG_H - 1 : y);
        const float* ra = Ab + (size_t)yc * IMG_W;
        const float* rb = Bb + (size_t)yc * IMG_W;
        am[ry] = *reinterpret_cast<const float4*>(ra + px);
        bm[ry] = *reinterpret_cast<const float4*>(rb + px);
        al[ry] = ra[xl];
        ar[ry] = ra[xr];
        bl[ry] = rb[xl];
        br[ry] = rb[xr];
    }
    // All loads above are straight-line; keep them above all compute.
    __builtin_amdgcn_sched_barrier(0);

    float vXa, vYa, vXb, vYb;
    sobel_var(am, al, ar, my, mlc, mrc, vXa, vYa);
    sobel_var(bm, bl, br, my, mlc, mrc, vXb, vYb);

    float dX = vXa - vXb, dY = vYa - vYb;
    float val = dX * dX + dY * dY;

    // wave (64-lane) tree reduction
#pragma unroll
    for (int off = 32; off > 0; off >>= 1) val += __shfl_down(val, off);
    __shared__ float ws[4];
    if ((t & 63) == 0) ws[t >> 6] = val;
    __syncthreads();
    if (t == 0) partial[wg] = ws[0] + ws[1] + ws[2] + ws[3];
}

__global__ __launch_bounds__(256) void gvl_final(const float* __restrict__ partial,
                                                 float* __restrict__ out) {
    int t = threadIdx.x;
    float s = 0.f;
#pragma unroll
    for (int i = 0; i < 16; ++i) s += partial[t + i * 256];
#pragma unroll
    for (int off = 32; off > 0; off >>= 1) s += __shfl_down(s, off);
    __shared__ float ws[4];
    if ((t & 63) == 0) ws[t >> 6] = s;
    __syncthreads();
    if (t == 0) out[0] = ws[0] + ws[1] + ws[2] + ws[3];
}

extern "C" void kernel_launch(void* const* d_in, const int* in_sizes, int n_in,
                              void* d_out, int out_size, void* d_ws, size_t ws_size,
                              hipStream_t stream) {
    const float* out_img = (const float*)d_in[0];
    const float* tgt_img = (const float*)d_in[1];
    float* partial = (float*)d_ws;   // 4096 floats = 16 KB
    gvl_main<<<4096, 256, 0, stream>>>(out_img, tgt_img, partial);
    gvl_final<<<1, 256, 0, stream>>>(partial, (float*)d_out);
}

// Round 4
// 45.554 us; speedup vs baseline: 1.0205x; 1.0062x over previous
//
#include <hip/hip_runtime.h>

#define IMG_H 1024
#define IMG_W 1024
#define LROWS 66      // 64 tile rows + 1 halo top + 1 halo bottom
#define LSTRIDE 76    // padded LDS row stride in floats (16B-aligned, bank-spread)
#define SEGS 18       // float4 segments per row: cols px0-4 .. px0+67
#define TOTSEG (2 * LROWS * SEGS)  // 2376 segment-loads per workgroup

// Separable Sobel, zero padding 1:
//   SOBEL_X = [1,2,1]^T (vert) x [-1,0,1] (horiz)
//   SOBEL_Y = [-1,0,1]^T (vert) x [ 1,2,1] (horiz)
// Grid: 16 images * 256 tiles; each WG = 64x64 pixel tile, 256 threads,
// one 4x4 block per thread. Tile + halo staged in LDS for BOTH images so
// all global loads batch before one barrier (MLP by construction).
__global__ __launch_bounds__(256) void gvl_main(const float* __restrict__ A,
                                                const float* __restrict__ B,
                                                float* __restrict__ partial) {
    __shared__ float lds[2][LROWS][LSTRIDE];

    int wg   = blockIdx.x;
    int img  = wg >> 8;
    int tile = wg & 255;
    int ty = tile >> 4, tx = tile & 15;
    int t  = threadIdx.x;
    int py0 = ty * 64, px0 = tx * 64;
    const size_t base = (size_t)img * (size_t)(IMG_H * IMG_W);
    const float* Ab = A + base;
    const float* Bb = B + base;

    auto stage_one = [&](int idx) {
        int im  = idx >= (LROWS * SEGS) ? 1 : 0;
        int rem = idx - im * (LROWS * SEGS);
        int row = rem / SEGS;              // const-div -> magic mul
        int seg = rem - row * SEGS;
        int y  = py0 - 1 + row;
        y  = y  < 0 ? 0 : (y  > IMG_H - 1 ? IMG_H - 1 : y);
        int x4 = px0 - 4 + 4 * seg;
        x4 = x4 < 0 ? 0 : (x4 > IMG_W - 4 ? IMG_W - 4 : x4);
        const float* p = im ? Bb : Ab;
        float4 v = *reinterpret_cast<const float4*>(p + (size_t)y * IMG_W + x4);
        *reinterpret_cast<float4*>(&lds[im][row][seg * 4]) = v;
    };

#pragma unroll
    for (int e = 0; e < 9; ++e) stage_one(t + 256 * e);   // 2304, always valid
    if (t < TOTSEG - 2304) stage_one(2304 + t);           // tail: 72
    __syncthreads();

    // ---- compute from LDS ----
    int by = t >> 4, bx = t & 15;
    int py = py0 + by * 4, px = px0 + bx * 4;
    float mlc = (px > 0) ? 1.f : 0.f;
    float mrc = (px + 4 < IMG_W) ? 1.f : 0.f;

    float vX[2], vY[2];
#pragma unroll
    for (int im = 0; im < 2; ++im) {
        float hA[6][4];  // horizontal [-1,0,1]
        float hB[6][4];  // horizontal [ 1,2,1]
#pragma unroll
        for (int ry = 0; ry < 6; ++ry) {
            float myr = ((unsigned)(py - 1 + ry) < (unsigned)IMG_H) ? 1.f : 0.f;
            const float* rp = &lds[im][by * 4 + ry][bx * 4];
            // window cols px-1..px+4 -> LDS cols bx*4+3 .. bx*4+8
            float  w0m = rp[3];
            float4 mid = *reinterpret_cast<const float4*>(rp + 4);
            float  w5m = rp[8];
            float w0 = w0m * mlc * myr;
            float w1 = mid.x * myr, w2 = mid.y * myr;
            float w3 = mid.z * myr, w4 = mid.w * myr;
            float w5 = w5m * mrc * myr;
            hA[ry][0] = w2 - w0;
            hA[ry][1] = w3 - w1;
            hA[ry][2] = w4 - w2;
            hA[ry][3] = w5 - w3;
            hB[ry][0] = w0 + 2.f * w1 + w2;
            hB[ry][1] = w1 + 2.f * w2 + w3;
            hB[ry][2] = w2 + 2.f * w3 + w4;
            hB[ry][3] = w3 + 2.f * w4 + w5;
        }
        float sX = 0.f, sX2 = 0.f, sY = 0.f, sY2 = 0.f;
#pragma unroll
        for (int yy = 0; yy < 4; ++yy) {
#pragma unroll
            for (int c = 0; c < 4; ++c) {
                float gx = hA[yy][c] + 2.f * hA[yy + 1][c] + hA[yy + 2][c];
                float gy = hB[yy + 2][c] - hB[yy][c];
                sX += gx; sX2 += gx * gx;
                sY += gy; sY2 += gy * gy;
            }
        }
        float mX = sX * 0.0625f, mY = sY * 0.0625f;
        vX[im] = sX2 * 0.0625f - mX * mX;
        vY[im] = sY2 * 0.0625f - mY * mY;
    }

    float dX = vX[0] - vX[1], dY = vY[0] - vY[1];
    float val = dX * dX + dY * dY;

    // wave (64-lane) tree reduction
#pragma unroll
    for (int off = 32; off > 0; off >>= 1) val += __shfl_down(val, off);
    __shared__ float ws[4];
    if ((t & 63) == 0) ws[t >> 6] = val;
    __syncthreads();
    if (t == 0) partial[wg] = ws[0] + ws[1] + ws[2] + ws[3];
}

__global__ __launch_bounds__(256) void gvl_final(const float* __restrict__ partial,
                                                 float* __restrict__ out) {
    int t = threadIdx.x;
    float s = 0.f;
#pragma unroll
    for (int i = 0; i < 16; ++i) s += partial[t + i * 256];
#pragma unroll
    for (int off = 32; off > 0; off >>= 1) s += __shfl_down(s, off);
    __shared__ float ws[4];
    if ((t & 63) == 0) ws[t >> 6] = s;
    __syncthreads();
    if (t == 0) out[0] = ws[0] + ws[1] + ws[2] + ws[3];
}

extern "C" void kernel_launch(void* const* d_in, const int* in_sizes, int n_in,
                              void* d_out, int out_size, void* d_ws, size_t ws_size,
                              hipStream_t stream) {
    const float* out_img = (const float*)d_in[0];
    const float* tgt_img = (const float*)d_in[1];
    float* partial = (float*)d_ws;   // 4096 floats = 16 KB
    gvl_main<<<4096, 256, 0, stream>>>(out_img, tgt_img, partial);
    gvl_final<<<1, 256, 0, stream>>>(partial, (float*)d_out);
}

// Round 5
// 28.651 us; speedup vs baseline: 1.6225x; 1.5900x over previous
//
#include <hip/hip_runtime.h>

#define IMG_H 1024
#define IMG_W 1024

// Streaming column-walk GradientVarianceLoss.
// 2048 waves = 16 images x 4 col-strips (256 cols) x 32 row-bands (32 rows).
// Each lane owns 4 columns; walks 34 input rows (band + 2 halo rows) for BOTH
// images; rolling separable Sobel (hA = [-1,0,1], hB = [1,2,1] horizontal;
// vertical combine at emit). One 4x4 block variance finalized every 4 rows.
// Software pipeline: next group's 24 loads issue before current group's
// compute, fully unrolled straight-line -> high MLP, no LDS, no barriers.

struct RowRegs { float4 ma, mb; float la, ra_, lb, rb_; };
struct HAB { float hA[4]; float hB[4]; };

__global__ __launch_bounds__(256) void gvl_main(const float* __restrict__ A,
                                                const float* __restrict__ B,
                                                float* __restrict__ partial) {
    const int t    = threadIdx.x;
    const int wave = (blockIdx.x << 2) | (t >> 6);   // 0..2047
    const int lane = t & 63;
    const int img   = wave >> 7;
    const int rem   = wave & 127;
    const int band  = rem >> 2;                      // 0..31, 32 rows each
    const int strip = rem & 3;                       // 0..3, 256 cols each
    const int y0    = band << 5;
    const int col0  = (strip << 8) | (lane << 2);

    const float* __restrict__ Ab = A + (size_t)img * (IMG_H * IMG_W);
    const float* __restrict__ Bb = B + (size_t)img * (IMG_H * IMG_W);

    const float mlc = (col0 > 0) ? 1.f : 0.f;            // left-col validity
    const float mrc = (col0 + 4 < IMG_W) ? 1.f : 0.f;    // right-col validity
    const int xl = (col0 > 0) ? col0 - 1 : 0;
    const int xr = (col0 + 4 < IMG_W) ? col0 + 4 : IMG_W - 1;
    const float zlast = (band == 31) ? 0.f : 1.f;        // row-1024 mask

    auto load_row = [&](int y, RowRegs& R) {
        int yc = y < IMG_H ? y : IMG_H - 1;              // clamp row 1024
        const float* ra = Ab + (size_t)yc * IMG_W;
        const float* rb = Bb + (size_t)yc * IMG_W;
        R.ma  = *reinterpret_cast<const float4*>(ra + col0);
        R.la  = ra[xl];  R.ra_ = ra[xr];
        R.mb  = *reinterpret_cast<const float4*>(rb + col0);
        R.lb  = rb[xl];  R.rb_ = rb[xr];
    };
    auto load_group = [&](RowRegs (&S)[4], int ys) {
#pragma unroll
        for (int r = 0; r < 4; ++r) load_row(ys + r, S[r]);
    };

    auto mk = [&](const float4 m, float l, float r, HAB& o) {
        float w0 = l * mlc, w5 = r * mrc;
        o.hA[0] = m.y - w0;  o.hA[1] = m.z - m.x;
        o.hA[2] = m.w - m.y; o.hA[3] = w5 - m.z;
        o.hB[0] = w0 + 2.f * m.x + m.y;
        o.hB[1] = m.x + 2.f * m.y + m.z;
        o.hB[2] = m.y + 2.f * m.z + m.w;
        o.hB[3] = m.z + 2.f * m.w + w5;
    };

    HAB a2, a1, b2, b1;   // carry: hA/hB of prev-2 and prev-1 input rows
    float loss = 0.f;

    auto emit = [&](const HAB& p2, const HAB& p1, const HAB& p0,
                    float& sX, float& sX2, float& sY, float& sY2) {
#pragma unroll
        for (int c = 0; c < 4; ++c) {
            float gx = p2.hA[c] + 2.f * p1.hA[c] + p0.hA[c];
            float gy = p0.hB[c] - p2.hB[c];
            sX += gx; sX2 += gx * gx;
            sY += gy; sY2 += gy * gy;
        }
    };

    auto do_group = [&](const RowRegs (&S)[4], float rm3) {
        float sXa = 0.f, sX2a = 0.f, sYa = 0.f, sY2a = 0.f;
        float sXb = 0.f, sX2b = 0.f, sYb = 0.f, sY2b = 0.f;
#pragma unroll
        for (int r = 0; r < 4; ++r) {
            HAB a0, b0;
            mk(S[r].ma, S[r].la, S[r].ra_, a0);
            mk(S[r].mb, S[r].lb, S[r].rb_, b0);
            if (r == 3) {   // possible image-bottom row (rm3==1.f folds away)
#pragma unroll
                for (int c = 0; c < 4; ++c) {
                    a0.hA[c] *= rm3; a0.hB[c] *= rm3;
                    b0.hA[c] *= rm3; b0.hB[c] *= rm3;
                }
            }
            emit(a2, a1, a0, sXa, sX2a, sYa, sY2a);
            emit(b2, b1, b0, sXb, sX2b, sYb, sY2b);
            a2 = a1; a1 = a0; b2 = b1; b1 = b0;
        }
        float mXa = sXa * 0.0625f, mYa = sYa * 0.0625f;
        float vXa = sX2a * 0.0625f - mXa * mXa;
        float vYa = sY2a * 0.0625f - mYa * mYa;
        float mXb = sXb * 0.0625f, mYb = sYb * 0.0625f;
        float vXb = sX2b * 0.0625f - mXb * mXb;
        float vYb = sY2b * 0.0625f - mYb * mYb;
        float dX = vXa - vXb, dY = vYa - vYb;
        loss += dX * dX + dY * dY;
    };

    // ---- prologue: rows y0-1, y0 + prefetch group 0 ----
    RowRegs P0, P1, N[4], M[4];
    const bool hasPrev = (band > 0);
    if (hasPrev) load_row(y0 - 1, P0);
    load_row(y0, P1);
    load_group(N, y0 + 1);
    if (hasPrev) {
        mk(P0.ma, P0.la, P0.ra_, a2);
        mk(P0.mb, P0.lb, P0.rb_, b2);
    } else {
#pragma unroll
        for (int c = 0; c < 4; ++c) { a2.hA[c] = a2.hB[c] = 0.f; b2.hA[c] = b2.hB[c] = 0.f; }
    }
    mk(P1.ma, P1.la, P1.ra_, a1);
    mk(P1.mb, P1.lb, P1.rb_, b1);

    // ---- 8 groups, software-pipelined (loads one group ahead) ----
#pragma unroll
    for (int i = 0; i < 4; ++i) {
        load_group(M, y0 + 8 * i + 5);            // group 2i+1 rows
        do_group(N, 1.f);                          // group 2i
        if (i < 3) load_group(N, y0 + 8 * i + 9);  // group 2i+2 rows
        do_group(M, (i == 3) ? zlast : 1.f);       // group 2i+1 (g7 may touch row 1024)
    }

    // ---- wave reduction, one partial per wave ----
#pragma unroll
    for (int off = 32; off > 0; off >>= 1) loss += __shfl_down(loss, off);
    if (lane == 0) partial[wave] = loss;
}

__global__ __launch_bounds__(256) void gvl_final(const float* __restrict__ partial,
                                                 float* __restrict__ out) {
    int t = threadIdx.x;
    float s = 0.f;
#pragma unroll
    for (int i = 0; i < 8; ++i) s += partial[t + (i << 8)];
#pragma unroll
    for (int off = 32; off > 0; off >>= 1) s += __shfl_down(s, off);
    __shared__ float ws[4];
    if ((t & 63) == 0) ws[t >> 6] = s;
    __syncthreads();
    if (t == 0) out[0] = ws[0] + ws[1] + ws[2] + ws[3];
}

extern "C" void kernel_launch(void* const* d_in, const int* in_sizes, int n_in,
                              void* d_out, int out_size, void* d_ws, size_t ws_size,
                              hipStream_t stream) {
    const float* out_img = (const float*)d_in[0];
    const float* tgt_img = (const float*)d_in[1];
    float* partial = (float*)d_ws;   // 2048 floats = 8 KB
    gvl_main<<<512, 256, 0, stream>>>(out_img, tgt_img, partial);
    gvl_final<<<1, 256, 0, stream>>>(partial, (float*)d_out);
}